// Round 7
// baseline (227.016 us; speedup 1.0000x reference)
//
#include <hip/hip_runtime.h>

typedef unsigned short ushort_t;
typedef short s8v __attribute__((ext_vector_type(8)));   // 8 x bf16 (4 VGPRs)
typedef float f4v __attribute__((ext_vector_type(4)));   // 4 x fp32 acc

#define DIMK   2048
#define NHEAD  32
#define HDIM   64
#define SCALE_LOG2E 0.18033688f   // 0.125 * log2(e): S arrives in log2 domain

__device__ __forceinline__ unsigned short f2bf(float f) {
    unsigned u = __float_as_uint(f);
    u += 0x7fffu + ((u >> 16) & 1u);           // RNE
    return (unsigned short)(u >> 16);
}

// pack two fp32 -> two bf16 (round-half-up) in one dword
__device__ __forceinline__ unsigned pack_bf2(float f0, float f1) {
    unsigned a = __float_as_uint(f0) + 0x8000u;
    unsigned b = __float_as_uint(f1) + 0x8000u;
    return __builtin_amdgcn_perm(b, a, 0x07060302u);
}

__device__ __forceinline__ float fexp2(float x) {
#if __has_builtin(__builtin_amdgcn_exp2f)
    return __builtin_amdgcn_exp2f(x);
#else
    return exp2f(x);
#endif
}

__device__ __forceinline__ void gll16(const void* g, void* l) {
    __builtin_amdgcn_global_load_lds(
        (const __attribute__((address_space(1))) void*)g,
        (__attribute__((address_space(3))) void*)l, 16, 0, 0);
}

__device__ __forceinline__ f4v mfma16(s8v a, s8v b, f4v c) {
    return __builtin_amdgcn_mfma_f32_16x16x32_bf16(a, b, c, 0, 0, 0);
}

// ---------------- fused fp32 -> bf16 cast of x + 4 weight matrices ----------------
__global__ __launch_bounds__(256) void cast_all(
    const float* __restrict__ x,  const float* __restrict__ wq,
    const float* __restrict__ wk, const float* __restrict__ wv,
    const float* __restrict__ wo,
    ushort_t* __restrict__ xb,  ushort_t* __restrict__ wqb,
    ushort_t* __restrict__ wkb, ushort_t* __restrict__ wvb,
    ushort_t* __restrict__ wob)
{
    int i = blockIdx.x * 256 + threadIdx.x;    // float4 unit index
    const float* src; ushort_t* dst;
    if      (i < 1048576) { src = x;  dst = xb; }
    else if (i < 2097152) { src = wq; dst = wqb; i -= 1048576; }
    else if (i < 2359296) { src = wk; dst = wkb; i -= 2097152; }
    else if (i < 2621440) { src = wv; dst = wvb; i -= 2359296; }
    else                  { src = wo; dst = wob; i -= 2621440; }
    float4 v = ((const float4*)src)[i];
    ushort4 o;
    o.x = f2bf(v.x); o.y = f2bf(v.y); o.z = f2bf(v.z); o.w = f2bf(v.w);
    ((ushort4*)dst)[i] = o;
}

// ---------------- GEMM core v2: C(128x64) = A(128xK) * Bt(64xK)^T ----------------
// BK=64 (32 steps, 16 MFMA/wave/step, 6 gll16/wave/step). XOR-swizzled LDS.
__device__ __forceinline__ void gemm_core64(
    const ushort_t* __restrict__ A, const ushort_t* __restrict__ Bt,
    int bm, int bn64, ushort_t* As, ushort_t* Bs, f4v acc[2][4])
{
    const int tid  = threadIdx.x;
    const int wave = tid >> 6, lane = tid & 63;
    const int c = lane & 15, q4 = lane >> 4;
    const int lrow = lane >> 3;                         // 0..7 within a gll16 group
    const int lchunk = (lane & 7) ^ lrow;               // swizzled source chunk

    const ushort_t* ag = A  + (size_t)(bm * 128 + wave * 32 + lrow) * DIMK + lchunk * 8;
    const ushort_t* bg = Bt + (size_t)(bn64 * 64 + wave * 16 + lrow) * DIMK + lchunk * 8;
    ushort_t* asw = As + (wave * 32) * 64;              // each gll16 covers 8 rows = 512 elems
    ushort_t* bsw = Bs + (wave * 16) * 64;

    const int Ra = wave * 32 + c;                       // A fragment rows: Ra, Ra+16
    for (int k0 = 0; k0 < DIMK; k0 += 64) {
        gll16(ag + k0,             asw);
        gll16(ag +  8 * DIMK + k0, asw + 512);
        gll16(ag + 16 * DIMK + k0, asw + 1024);
        gll16(ag + 24 * DIMK + k0, asw + 1536);
        gll16(bg + k0,             bsw);
        gll16(bg +  8 * DIMK + k0, bsw + 512);
        __syncthreads();
        s8v af[2][2], bfv[4][2];
#pragma unroll
        for (int mt = 0; mt < 2; ++mt)
#pragma unroll
            for (int kc = 0; kc < 2; ++kc) {
                int R = Ra + mt * 16;
                af[mt][kc] = *(const s8v*)(As + (R * 8 + ((kc * 4 + q4) ^ (R & 7))) * 8);
            }
#pragma unroll
        for (int nt = 0; nt < 4; ++nt)
#pragma unroll
            for (int kc = 0; kc < 2; ++kc) {
                int R = nt * 16 + c;
                bfv[nt][kc] = *(const s8v*)(Bs + (R * 8 + ((kc * 4 + q4) ^ (R & 7))) * 8);
            }
#pragma unroll
        for (int kc = 0; kc < 2; ++kc)
#pragma unroll
            for (int mt = 0; mt < 2; ++mt)
#pragma unroll
                for (int nt = 0; nt < 4; ++nt)
                    acc[mt][nt] = mfma16(af[mt][kc], bfv[nt][kc], acc[mt][nt]);
        __syncthreads();
    }
}

// ---------------- fused QKV projection + bias + RoPE; LDS-routed coalesced epilogues ----------------
// grid (48,16): nb 0..31 -> Q head-tiles, 32..39 -> K blocked, 40..47 -> V blocked+perm
__global__ __launch_bounds__(256) void qkv_gemm(
    const ushort_t* __restrict__ Xb,
    const ushort_t* __restrict__ Wqb, const ushort_t* __restrict__ Wkb, const ushort_t* __restrict__ Wvb,
    const float* __restrict__ biasq, const float* __restrict__ biask, const float* __restrict__ biasv,
    const float* __restrict__ rope,
    ushort_t* __restrict__ Qo, ushort_t* __restrict__ Kblk, ushort_t* __restrict__ Vblk)
{
    __shared__ ushort_t SM[12288];           // 24 KB: GEMM staging, then epilogue staging
    ushort_t* As = SM;                       // 128*64 = 8192 elems
    ushort_t* Bs = SM + 8192;                //  64*64 = 4096 elems
    const int nb = blockIdx.x, bm = blockIdx.y;
    const ushort_t* Bt; const float* bias; int nbl, mode;
    if      (nb < 32) { Bt = Wqb; bias = biasq; nbl = nb;      mode = 0; }
    else if (nb < 40) { Bt = Wkb; bias = biask; nbl = nb - 32; mode = 1; }
    else              { Bt = Wvb; bias = biasv; nbl = nb - 40; mode = 2; }

    const f4v fz = {0.f, 0.f, 0.f, 0.f};
    f4v acc[2][4];
    for (int i = 0; i < 2; ++i) for (int j = 0; j < 4; ++j) acc[i][j] = fz;

    gemm_core64(Xb, Bt, bm, nbl, As, Bs, acc);

    const int tid = threadIdx.x, wave = tid >> 6, lane = tid & 63;
    const int c = lane & 15, q4 = lane >> 4;

    // ---- stage transformed outputs into SM at their layout-local offset ----
    if (mode == 0) {                                     // Q: bias + RoPE + scale*log2e; SM row-major 128x64
#pragma unroll
        for (int mt = 0; mt < 2; ++mt)
#pragma unroll
            for (int r = 0; r < 4; ++r) {
                int rowl = wave * 32 + mt * 16 + q4 * 4 + r;
                int row  = bm * 128 + rowl;
                const float* rp = rope + row * 64;
#pragma unroll
                for (int nt = 0; nt < 2; ++nt) {
                    int d   = nt * 16 + c;
                    int col = nbl * 64 + d;
                    float cs = rp[d], sn = rp[32 + d];
                    float x1 = acc[mt][nt][r]     + bias[col];
                    float x2 = acc[mt][nt + 2][r] + bias[col + 32];
                    SM[rowl * 64 + d]      = f2bf((x1 * cs - x2 * sn) * SCALE_LOG2E);
                    SM[rowl * 64 + d + 32] = f2bf((x1 * sn + x2 * cs) * SCALE_LOG2E);
                }
            }
    } else if (mode == 1) {                              // K: bias + RoPE -> blocked local offset
#pragma unroll
        for (int mt = 0; mt < 2; ++mt)
#pragma unroll
            for (int r = 0; r < 4; ++r) {
                int rowl = wave * 32 + mt * 16 + q4 * 4 + r;
                int row  = bm * 128 + rowl;
                const float* rp = rope + row * 64;
                int tl  = rowl >> 6;                     // which of the 2 key-tiles in this block
                int ntk = (rowl & 63) >> 4, ck = rowl & 15;
#pragma unroll
                for (int nt = 0; nt < 2; ++nt) {
                    int d   = nt * 16 + c;
                    int col = nbl * 64 + d;
                    float cs = rp[d], sn = rp[32 + d];
                    float x1 = acc[mt][nt][r]     + bias[col];
                    float x2 = acc[mt][nt + 2][r] + bias[col + 32];
                    float o1 = x1 * cs - x2 * sn;        // dim d
                    float o2 = x1 * sn + x2 * cs;        // dim d+32
                    {   int dd = d;       int kc = dd >> 5, q4k = (dd >> 3) & 3, j = dd & 7;
                        SM[tl * 4096 + ((kc * 4 + ntk) * 64 + q4k * 16 + ck) * 8 + j] = f2bf(o1); }
                    {   int dd = d + 32;  int kc = dd >> 5, q4k = (dd >> 3) & 3, j = dd & 7;
                        SM[tl * 4096 + ((kc * 4 + ntk) * 64 + q4k * 16 + ck) * 8 + j] = f2bf(o2); }
                }
            }
    } else {                                             // V: bias -> blocked + sigma key-perm local offset
#pragma unroll
        for (int mt = 0; mt < 2; ++mt)
#pragma unroll
            for (int nt = 0; nt < 4; ++nt)
#pragma unroll
                for (int r = 0; r < 4; ++r) {
                    int rowl = wave * 32 + mt * 16 + q4 * 4 + r;
                    int col  = nbl * 64 + nt * 16 + c;
                    int tl = rowl >> 6, K64 = rowl & 63;
                    int kp = (K64 & 15) * 4 + (K64 >> 4);            // sigma
                    int kc = kp >> 5, q4v = (kp >> 3) & 3, j = kp & 7;
                    SM[tl * 4096 + ((kc * 4 + nt) * 64 + q4v * 16 + c) * 8 + j]
                        = f2bf(acc[mt][nt][r] + bias[col]);
                }
    }
    __syncthreads();

    // ---- coalesced copy-out: 1024 chunks of 16B, 4 per thread ----
    if (mode == 0) {
#pragma unroll
        for (int i = 0; i < 4; ++i) {
            int idx  = i * 256 + tid;                    // chunk index
            int rowl = idx >> 3, c8 = (idx & 7) * 8;
            *(int4*)(Qo + (size_t)(bm * 128 + rowl) * 2048 + nbl * 64 + c8)
                = *(const int4*)(SM + idx * 8);
        }
    } else {
        ushort_t* dstb = (mode == 1 ? Kblk : Vblk) + ((size_t)nbl * 32 + bm * 2) * 4096;
#pragma unroll
        for (int i = 0; i < 4; ++i) {
            int idx = i * 256 + tid;
            *(int4*)(dstb + idx * 8) = *(const int4*)(SM + idx * 8);
        }
    }
}

// ---------------- output projection: grid (32,16), 128M x 64N tiles ----------------
__global__ __launch_bounds__(256) void proj_gemm(
    const ushort_t* __restrict__ Ob, const ushort_t* __restrict__ Wob,
    const float* __restrict__ bias, float* __restrict__ Co)
{
    __shared__ ushort_t SM[12288];
    ushort_t* As = SM;
    ushort_t* Bs = SM + 8192;
    const f4v fz = {0.f, 0.f, 0.f, 0.f};
    f4v acc[2][4];
    for (int i = 0; i < 2; ++i) for (int j = 0; j < 4; ++j) acc[i][j] = fz;

    gemm_core64(Ob, Wob, blockIdx.y, blockIdx.x, As, Bs, acc);

    const int tid = threadIdx.x, wave = tid >> 6, lane = tid & 63;
    const int c = lane & 15, q4 = lane >> 4;
#pragma unroll
    for (int mt = 0; mt < 2; ++mt)
#pragma unroll
        for (int nt = 0; nt < 4; ++nt)
#pragma unroll
            for (int r = 0; r < 4; ++r) {
                int row = blockIdx.y * 128 + wave * 32 + mt * 16 + q4 * 4 + r;
                int col = blockIdx.x * 64 + nt * 16 + c;
                Co[(size_t)row * 2048 + col] = acc[mt][nt][r] + bias[col];
            }
}

// ---------------- flash attention: LDS-shared K/V across 4 heads of a kv-group ----------------
// grid (64, 8): block = (query subtile qq = 63-blockIdx.x [LPT], kvh = blockIdx.y).
// Wave w handles head kvh*4+w on queries [qq*32, qq*32+32). All waves share the K/V tile,
// staged double-buffered via global_load_lds; ONE barrier per iter (drains prefetch + guards buffer).
__global__ __launch_bounds__(256) void attn_kernel(
    const ushort_t* __restrict__ Qb,    // (2048, 2048) roped, prescaled by 0.125*log2e
    const ushort_t* __restrict__ Kblk,  // blocked: per (kvh,kt) contiguous 4096 elems
    const ushort_t* __restrict__ Vblk,  // blocked + sigma key-perm
    const float* __restrict__ sinks,
    ushort_t* __restrict__ Ob)          // (2048, 2048)
{
    __shared__ ushort_t KV[2][8192];        // [buf][ K:0..4095 | V:4096..8191 ]
    __shared__ ushort_t Ps[4][32 * 72];     // per-wave P scratch, pitch 72
    const int qq = 63 - blockIdx.x, kvh = blockIdx.y;
    const int tid = threadIdx.x, wave = tid >> 6, lane = tid & 63;
    const int c = lane & 15, q4 = lane >> 4;
    const int h  = kvh * 4 + wave;
    const int q0 = qq * 32;
    const int nkt = (qq >> 1) + 1;          // causal: key tiles 0..nkt-1
    ushort_t* Pw = &Ps[wave][0];

    s8v qf[2][2];
#pragma unroll
    for (int mi = 0; mi < 2; ++mi)
#pragma unroll
        for (int kc = 0; kc < 2; ++kc)
            qf[mi][kc] = *(const s8v*)(Qb + (size_t)(q0 + mi * 16 + c) * 2048 + h * 64 + kc * 32 + q4 * 8);

    const f4v fz = {0.f, 0.f, 0.f, 0.f};
    f4v Oacc[2][4];
    float Lp[2][4];
#pragma unroll
    for (int mi = 0; mi < 2; ++mi) {
#pragma unroll
        for (int dt = 0; dt < 4; ++dt) Oacc[mi][dt] = fz;
#pragma unroll
        for (int r = 0; r < 4; ++r) Lp[mi][r] = 0.f;
    }

    const ushort_t* kg = Kblk + (size_t)kvh * 32 * 4096 + lane * 8;   // per-lane source base
    const ushort_t* vg = Vblk + (size_t)kvh * 32 * 4096 + lane * 8;

    // stage(kt, buf): 16 gll16 chunks of 1KB, 4 per wave (2 K + 2 V)
#define ATTN_STAGE(KT, BUF)                                                    \
    do {                                                                       \
        ushort_t* db_ = &KV[BUF][0];                                           \
        _Pragma("unroll")                                                      \
        for (int i_ = 0; i_ < 2; ++i_) {                                       \
            int ch_ = wave * 2 + i_;                                           \
            gll16(kg + (size_t)(KT) * 4096 + ch_ * 512, db_ + ch_ * 512);      \
            gll16(vg + (size_t)(KT) * 4096 + ch_ * 512, db_ + 4096 + ch_ * 512); \
        }                                                                      \
    } while (0)

    ATTN_STAGE(0, 0);
    __syncthreads();

    for (int kt = 0; kt < nkt; ++kt) {
        const int buf = kt & 1;
        if (kt + 1 < nkt) ATTN_STAGE(kt + 1, buf ^ 1);   // prefetch next tile
        const ushort_t* kb_ = &KV[buf][0];
        const ushort_t* vb_ = &KV[buf][4096];

        // S = Q K^T (fragments straight from LDS)
        f4v S[2][4];
#pragma unroll
        for (int mi = 0; mi < 2; ++mi)
#pragma unroll
            for (int nt = 0; nt < 4; ++nt) S[mi][nt] = fz;
#pragma unroll
        for (int kc = 0; kc < 2; ++kc)
#pragma unroll
            for (int nt = 0; nt < 4; ++nt) {
                s8v kf = *(const s8v*)(kb_ + ((kc * 4 + nt) * 64 + lane) * 8);
#pragma unroll
                for (int mi = 0; mi < 2; ++mi)
                    S[mi][nt] = mfma16(qf[mi][kc], kf, S[mi][nt]);
            }

        if (kt == nkt - 1) {                             // diagonal tile: causal mask
#pragma unroll
            for (int mi = 0; mi < 2; ++mi)
#pragma unroll
                for (int nt = 0; nt < 4; ++nt) {
                    int key = kt * 64 + nt * 16 + c;
#pragma unroll
                    for (int r = 0; r < 4; ++r) {
                        int qrow = q0 + mi * 16 + q4 * 4 + r;
                        if (key > qrow) S[mi][nt][r] = -1.0e30f;
                    }
                }
        }

        // exp2 (log2 domain), accumulate L, pack 4 bf16 -> one b64 LDS write per (mi,r)
#pragma unroll
        for (int mi = 0; mi < 2; ++mi)
#pragma unroll
            for (int r = 0; r < 4; ++r) {
                float p0 = fexp2(S[mi][0][r]), p1 = fexp2(S[mi][1][r]);
                float p2 = fexp2(S[mi][2][r]), p3 = fexp2(S[mi][3][r]);
                Lp[mi][r] += (p0 + p1) + (p2 + p3);
                int2 w_; w_.x = (int)pack_bf2(p0, p1); w_.y = (int)pack_bf2(p2, p3);
                *(int2*)(Pw + (mi * 16 + q4 * 4 + r) * 72 + c * 4) = w_;   // sigma: k' = c*4+nt
            }
        s8v pa[2][2];
#pragma unroll
        for (int mi = 0; mi < 2; ++mi)
#pragma unroll
            for (int kc = 0; kc < 2; ++kc)
                pa[mi][kc] = *(const s8v*)(Pw + (mi * 16 + c) * 72 + kc * 32 + q4 * 8);

        // O += P @ V (V fragments straight from LDS; sigma folded into Vblk)
#pragma unroll
        for (int kc = 0; kc < 2; ++kc)
#pragma unroll
            for (int dt = 0; dt < 4; ++dt) {
                s8v vf = *(const s8v*)(vb_ + ((kc * 4 + dt) * 64 + lane) * 8);
#pragma unroll
                for (int mi = 0; mi < 2; ++mi)
                    Oacc[mi][dt] = mfma16(pa[mi][kc], vf, Oacc[mi][dt]);
            }
        __syncthreads();   // drains next-tile prefetch + protects buffer reuse
    }
#undef ATTN_STAGE

    // end-of-wave L reduction across the 16 key-col lanes
#pragma unroll
    for (int mi = 0; mi < 2; ++mi)
#pragma unroll
        for (int r = 0; r < 4; ++r)
#pragma unroll
            for (int off = 1; off < 16; off <<= 1)
                Lp[mi][r] += __shfl_xor(Lp[mi][r], off);

    const float sk = sinks[h];
#pragma unroll
    for (int mi = 0; mi < 2; ++mi)
#pragma unroll
        for (int r = 0; r < 4; ++r) {
            float L = Lp[mi][r];
            float lse = __logf(L);
            float sig = 1.f / (1.f + __expf(sk - lse));
            float sc  = sig / L;
            int row = q0 + mi * 16 + q4 * 4 + r;
#pragma unroll
            for (int dt = 0; dt < 4; ++dt)
                Ob[(size_t)row * 2048 + h * 64 + dt * 16 + c] = f2bf(Oacc[mi][dt][r] * sc);
        }
}

// ---------------- launch ----------------
extern "C" void kernel_launch(void* const* d_in, const int* in_sizes, int n_in,
                              void* d_out, int out_size, void* d_ws, size_t ws_size,
                              hipStream_t stream)
{
    (void)in_sizes; (void)n_in; (void)out_size; (void)ws_size;
    const float* x     = (const float*)d_in[0];
    const float* rope  = (const float*)d_in[1];
    const float* wq    = (const float*)d_in[2];
    const float* qb    = (const float*)d_in[3];
    const float* wk    = (const float*)d_in[4];
    const float* kb    = (const float*)d_in[5];
    const float* wv    = (const float*)d_in[6];
    const float* vb    = (const float*)d_in[7];
    const float* wo    = (const float*)d_in[8];
    const float* wob_f = (const float*)d_in[9];
    const float* sinks = (const float*)d_in[10];
    float* out = (float*)d_out;

    char* ws = (char*)d_ws;
    ushort_t* xb   = (ushort_t*)(ws);                       //  0 .. 8 MB   x bf16
    ushort_t* wqb  = (ushort_t*)(ws + (8ull  << 20));       //  8 .. 16     wq bf16
    ushort_t* wkb  = (ushort_t*)(ws + (16ull << 20));       // 16 .. 18     wk bf16
    ushort_t* wvb  = (ushort_t*)(ws + (18ull << 20));       // 18 .. 20     wv bf16
    ushort_t* wob  = (ushort_t*)(ws + (20ull << 20));       // 20 .. 28     wo bf16
    ushort_t* qo   = (ushort_t*)(ws + (28ull << 20));       // 28 .. 36     Q roped*scale*log2e
    ushort_t* kblk = (ushort_t*)(ws + (36ull << 20));       // 36 .. 38     K blocked
    ushort_t* vblk = (ushort_t*)(ws + (38ull << 20));       // 38 .. 40     V blocked
    ushort_t* ao   = (ushort_t*)(ws + (40ull << 20));       // 40 .. 48     attn out

    cast_all<<<14336, 256, 0, stream>>>(x, wq, wk, wv, wo, xb, wqb, wkb, wvb, wob);
    qkv_gemm<<<dim3(48, 16), 256, 0, stream>>>(xb, wqb, wkb, wvb, qb, kb, vb, rope, qo, kblk, vblk);
    attn_kernel<<<dim3(64, 8), 256, 0, stream>>>(qo, kblk, vblk, sinks, ao);
    proj_gemm<<<dim3(32, 16), 256, 0, stream>>>(ao, wob, wob_f, out);
}

// Round 8
// 215.794 us; speedup vs baseline: 1.0520x; 1.0520x over previous
//
#include <hip/hip_runtime.h>

typedef unsigned short ushort_t;
typedef short s8v __attribute__((ext_vector_type(8)));   // 8 x bf16 (4 VGPRs)
typedef float f4v __attribute__((ext_vector_type(4)));   // 4 x fp32 acc

#define DIMK   2048
#define NHEAD  32
#define HDIM   64
#define SCALE_LOG2E 0.18033688f   // 0.125 * log2(e): S arrives in log2 domain

__device__ __forceinline__ unsigned short f2bf(float f) {
    unsigned u = __float_as_uint(f);
    u += 0x7fffu + ((u >> 16) & 1u);           // RNE
    return (unsigned short)(u >> 16);
}

// pack two fp32 -> two bf16 (round-half-up) in one dword
__device__ __forceinline__ unsigned pack_bf2(float f0, float f1) {
    unsigned a = __float_as_uint(f0) + 0x8000u;
    unsigned b = __float_as_uint(f1) + 0x8000u;
    return __builtin_amdgcn_perm(b, a, 0x07060302u);
}

__device__ __forceinline__ float fexp2(float x) {
#if __has_builtin(__builtin_amdgcn_exp2f)
    return __builtin_amdgcn_exp2f(x);
#else
    return exp2f(x);
#endif
}

__device__ __forceinline__ void gll16(const void* g, void* l) {
    __builtin_amdgcn_global_load_lds(
        (const __attribute__((address_space(1))) void*)g,
        (__attribute__((address_space(3))) void*)l, 16, 0, 0);
}

__device__ __forceinline__ f4v mfma16(s8v a, s8v b, f4v c) {
    return __builtin_amdgcn_mfma_f32_16x16x32_bf16(a, b, c, 0, 0, 0);
}

// ---------------- fused fp32 -> bf16 cast of x + 4 weight matrices ----------------
__global__ __launch_bounds__(256) void cast_all(
    const float* __restrict__ x,  const float* __restrict__ wq,
    const float* __restrict__ wk, const float* __restrict__ wv,
    const float* __restrict__ wo,
    ushort_t* __restrict__ xb,  ushort_t* __restrict__ wqb,
    ushort_t* __restrict__ wkb, ushort_t* __restrict__ wvb,
    ushort_t* __restrict__ wob)
{
    int i = blockIdx.x * 256 + threadIdx.x;    // float4 unit index
    const float* src; ushort_t* dst;
    if      (i < 1048576) { src = x;  dst = xb; }
    else if (i < 2097152) { src = wq; dst = wqb; i -= 1048576; }
    else if (i < 2359296) { src = wk; dst = wkb; i -= 2097152; }
    else if (i < 2621440) { src = wv; dst = wvb; i -= 2359296; }
    else                  { src = wo; dst = wob; i -= 2621440; }
    float4 v = ((const float4*)src)[i];
    ushort4 o;
    o.x = f2bf(v.x); o.y = f2bf(v.y); o.z = f2bf(v.z); o.w = f2bf(v.w);
    ((ushort4*)dst)[i] = o;
}

// ---------------- GEMM core v2: C(128x64) = A(128xK) * Bt(64xK)^T ----------------
// BK=64 (32 steps, 16 MFMA/wave/step, 6 gll16/wave/step). XOR-swizzled LDS.
__device__ __forceinline__ void gemm_core64(
    const ushort_t* __restrict__ A, const ushort_t* __restrict__ Bt,
    int bm, int bn64, ushort_t* As, ushort_t* Bs, f4v acc[2][4])
{
    const int tid  = threadIdx.x;
    const int wave = tid >> 6, lane = tid & 63;
    const int c = lane & 15, q4 = lane >> 4;
    const int lrow = lane >> 3;                         // 0..7 within a gll16 group
    const int lchunk = (lane & 7) ^ lrow;               // swizzled source chunk

    const ushort_t* ag = A  + (size_t)(bm * 128 + wave * 32 + lrow) * DIMK + lchunk * 8;
    const ushort_t* bg = Bt + (size_t)(bn64 * 64 + wave * 16 + lrow) * DIMK + lchunk * 8;
    ushort_t* asw = As + (wave * 32) * 64;              // each gll16 covers 8 rows = 512 elems
    ushort_t* bsw = Bs + (wave * 16) * 64;

    const int Ra = wave * 32 + c;                       // A fragment rows: Ra, Ra+16
    for (int k0 = 0; k0 < DIMK; k0 += 64) {
        gll16(ag + k0,             asw);
        gll16(ag +  8 * DIMK + k0, asw + 512);
        gll16(ag + 16 * DIMK + k0, asw + 1024);
        gll16(ag + 24 * DIMK + k0, asw + 1536);
        gll16(bg + k0,             bsw);
        gll16(bg +  8 * DIMK + k0, bsw + 512);
        __syncthreads();
        s8v af[2][2], bfv[4][2];
#pragma unroll
        for (int mt = 0; mt < 2; ++mt)
#pragma unroll
            for (int kc = 0; kc < 2; ++kc) {
                int R = Ra + mt * 16;
                af[mt][kc] = *(const s8v*)(As + (R * 8 + ((kc * 4 + q4) ^ (R & 7))) * 8);
            }
#pragma unroll
        for (int nt = 0; nt < 4; ++nt)
#pragma unroll
            for (int kc = 0; kc < 2; ++kc) {
                int R = nt * 16 + c;
                bfv[nt][kc] = *(const s8v*)(Bs + (R * 8 + ((kc * 4 + q4) ^ (R & 7))) * 8);
            }
#pragma unroll
        for (int kc = 0; kc < 2; ++kc)
#pragma unroll
            for (int mt = 0; mt < 2; ++mt)
#pragma unroll
                for (int nt = 0; nt < 4; ++nt)
                    acc[mt][nt] = mfma16(af[mt][kc], bfv[nt][kc], acc[mt][nt]);
        __syncthreads();
    }
}

// ---------------- fused QKV projection + bias + RoPE; LDS-routed coalesced epilogues ----------------
// grid (48,16): nb 0..31 -> Q head-tiles, 32..39 -> K blocked, 40..47 -> V blocked+perm
__global__ __launch_bounds__(256) void qkv_gemm(
    const ushort_t* __restrict__ Xb,
    const ushort_t* __restrict__ Wqb, const ushort_t* __restrict__ Wkb, const ushort_t* __restrict__ Wvb,
    const float* __restrict__ biasq, const float* __restrict__ biask, const float* __restrict__ biasv,
    const float* __restrict__ rope,
    ushort_t* __restrict__ Qo, ushort_t* __restrict__ Kblk, ushort_t* __restrict__ Vblk)
{
    __shared__ ushort_t SM[12288];           // 24 KB: GEMM staging, then epilogue staging
    ushort_t* As = SM;                       // 128*64 = 8192 elems
    ushort_t* Bs = SM + 8192;                //  64*64 = 4096 elems
    const int nb = blockIdx.x, bm = blockIdx.y;
    const ushort_t* Bt; const float* bias; int nbl, mode;
    if      (nb < 32) { Bt = Wqb; bias = biasq; nbl = nb;      mode = 0; }
    else if (nb < 40) { Bt = Wkb; bias = biask; nbl = nb - 32; mode = 1; }
    else              { Bt = Wvb; bias = biasv; nbl = nb - 40; mode = 2; }

    const f4v fz = {0.f, 0.f, 0.f, 0.f};
    f4v acc[2][4];
    for (int i = 0; i < 2; ++i) for (int j = 0; j < 4; ++j) acc[i][j] = fz;

    gemm_core64(Xb, Bt, bm, nbl, As, Bs, acc);

    const int tid = threadIdx.x, wave = tid >> 6, lane = tid & 63;
    const int c = lane & 15, q4 = lane >> 4;

    // ---- stage transformed outputs into SM at their layout-local offset ----
    if (mode == 0) {                                     // Q: bias + RoPE + scale*log2e; SM row-major 128x64
#pragma unroll
        for (int mt = 0; mt < 2; ++mt)
#pragma unroll
            for (int r = 0; r < 4; ++r) {
                int rowl = wave * 32 + mt * 16 + q4 * 4 + r;
                int row  = bm * 128 + rowl;
                const float* rp = rope + row * 64;
#pragma unroll
                for (int nt = 0; nt < 2; ++nt) {
                    int d   = nt * 16 + c;
                    int col = nbl * 64 + d;
                    float cs = rp[d], sn = rp[32 + d];
                    float x1 = acc[mt][nt][r]     + bias[col];
                    float x2 = acc[mt][nt + 2][r] + bias[col + 32];
                    SM[rowl * 64 + d]      = f2bf((x1 * cs - x2 * sn) * SCALE_LOG2E);
                    SM[rowl * 64 + d + 32] = f2bf((x1 * sn + x2 * cs) * SCALE_LOG2E);
                }
            }
    } else if (mode == 1) {                              // K: bias + RoPE -> blocked local offset
#pragma unroll
        for (int mt = 0; mt < 2; ++mt)
#pragma unroll
            for (int r = 0; r < 4; ++r) {
                int rowl = wave * 32 + mt * 16 + q4 * 4 + r;
                int row  = bm * 128 + rowl;
                const float* rp = rope + row * 64;
                int tl  = rowl >> 6;                     // which of the 2 key-tiles in this block
                int ntk = (rowl & 63) >> 4, ck = rowl & 15;
#pragma unroll
                for (int nt = 0; nt < 2; ++nt) {
                    int d   = nt * 16 + c;
                    int col = nbl * 64 + d;
                    float cs = rp[d], sn = rp[32 + d];
                    float x1 = acc[mt][nt][r]     + bias[col];
                    float x2 = acc[mt][nt + 2][r] + bias[col + 32];
                    float o1 = x1 * cs - x2 * sn;        // dim d
                    float o2 = x1 * sn + x2 * cs;        // dim d+32
                    {   int dd = d;       int kc = dd >> 5, q4k = (dd >> 3) & 3, j = dd & 7;
                        SM[tl * 4096 + ((kc * 4 + ntk) * 64 + q4k * 16 + ck) * 8 + j] = f2bf(o1); }
                    {   int dd = d + 32;  int kc = dd >> 5, q4k = (dd >> 3) & 3, j = dd & 7;
                        SM[tl * 4096 + ((kc * 4 + ntk) * 64 + q4k * 16 + ck) * 8 + j] = f2bf(o2); }
                }
            }
    } else {                                             // V: bias -> blocked + sigma key-perm local offset
#pragma unroll
        for (int mt = 0; mt < 2; ++mt)
#pragma unroll
            for (int nt = 0; nt < 4; ++nt)
#pragma unroll
                for (int r = 0; r < 4; ++r) {
                    int rowl = wave * 32 + mt * 16 + q4 * 4 + r;
                    int col  = nbl * 64 + nt * 16 + c;
                    int tl = rowl >> 6, K64 = rowl & 63;
                    int kp = (K64 & 15) * 4 + (K64 >> 4);            // sigma
                    int kc = kp >> 5, q4v = (kp >> 3) & 3, j = kp & 7;
                    SM[tl * 4096 + ((kc * 4 + nt) * 64 + q4v * 16 + c) * 8 + j]
                        = f2bf(acc[mt][nt][r] + bias[col]);
                }
    }
    __syncthreads();

    // ---- coalesced copy-out: 1024 chunks of 16B, 4 per thread ----
    if (mode == 0) {
#pragma unroll
        for (int i = 0; i < 4; ++i) {
            int idx  = i * 256 + tid;                    // chunk index
            int rowl = idx >> 3, c8 = (idx & 7) * 8;
            *(int4*)(Qo + (size_t)(bm * 128 + rowl) * 2048 + nbl * 64 + c8)
                = *(const int4*)(SM + idx * 8);
        }
    } else {
        ushort_t* dstb = (mode == 1 ? Kblk : Vblk) + ((size_t)nbl * 32 + bm * 2) * 4096;
#pragma unroll
        for (int i = 0; i < 4; ++i) {
            int idx = i * 256 + tid;
            *(int4*)(dstb + idx * 8) = *(const int4*)(SM + idx * 8);
        }
    }
}

// ---------------- output projection: grid (32,16), 128M x 64N tiles ----------------
__global__ __launch_bounds__(256) void proj_gemm(
    const ushort_t* __restrict__ Ob, const ushort_t* __restrict__ Wob,
    const float* __restrict__ bias, float* __restrict__ Co)
{
    __shared__ ushort_t SM[12288];
    ushort_t* As = SM;
    ushort_t* Bs = SM + 8192;
    const f4v fz = {0.f, 0.f, 0.f, 0.f};
    f4v acc[2][4];
    for (int i = 0; i < 2; ++i) for (int j = 0; j < 4; ++j) acc[i][j] = fz;

    gemm_core64(Ob, Wob, blockIdx.y, blockIdx.x, As, Bs, acc);

    const int tid = threadIdx.x, wave = tid >> 6, lane = tid & 63;
    const int c = lane & 15, q4 = lane >> 4;
#pragma unroll
    for (int mt = 0; mt < 2; ++mt)
#pragma unroll
        for (int nt = 0; nt < 4; ++nt)
#pragma unroll
            for (int r = 0; r < 4; ++r) {
                int row = blockIdx.y * 128 + wave * 32 + mt * 16 + q4 * 4 + r;
                int col = blockIdx.x * 64 + nt * 16 + c;
                Co[(size_t)row * 2048 + col] = acc[mt][nt][r] + bias[col];
            }
}

// ---------------- barrier-free flash attention, 128-thread blocks, LPT dispatch ----------------
// grid (32, 32): block = (q-tile t = 31-blockIdx.x [longest first], head = blockIdx.y).
// 2 waves/block; wave w owns queries [t*64 + w*32, +32). No __syncthreads, no prefetch.
// All waves in a block run the same iter count -> zero intra-block wave-slot waste;
// 1024 small blocks + descending-work dispatch order = greedy LPT across CUs.
__global__ __launch_bounds__(128) void attn_kernel(
    const ushort_t* __restrict__ Qb,    // (2048, 2048) roped, prescaled by 0.125*log2e
    const ushort_t* __restrict__ Kblk,  // blocked
    const ushort_t* __restrict__ Vblk,  // blocked + sigma perm
    const float* __restrict__ sinks,
    ushort_t* __restrict__ Ob)          // (2048, 2048)
{
    __shared__ ushort_t Ps[2][32 * 72];     // per-wave P scratch, pitch 72
    const int t = 31 - blockIdx.x, h = blockIdx.y, kvh = h >> 2;
    const int tid = threadIdx.x, wave = tid >> 6, lane = tid & 63;
    const int c = lane & 15, q4 = lane >> 4;
    const int q0 = t * 64 + wave * 32;
    ushort_t* Pw = &Ps[wave][0];

    s8v qf[2][2];
#pragma unroll
    for (int mi = 0; mi < 2; ++mi)
#pragma unroll
        for (int kc = 0; kc < 2; ++kc)
            qf[mi][kc] = *(const s8v*)(Qb + (size_t)(q0 + mi * 16 + c) * 2048 + h * 64 + kc * 32 + q4 * 8);

    const f4v fz = {0.f, 0.f, 0.f, 0.f};
    f4v Oacc[2][4];
    float Lp[2][4];
#pragma unroll
    for (int mi = 0; mi < 2; ++mi) {
#pragma unroll
        for (int dt = 0; dt < 4; ++dt) Oacc[mi][dt] = fz;
#pragma unroll
        for (int r = 0; r < 4; ++r) Lp[mi][r] = 0.f;
    }

    const ushort_t* kbase = Kblk + (size_t)kvh * 32 * 4096;
    const ushort_t* vbase = Vblk + (size_t)kvh * 32 * 4096;

    for (int kt = 0; kt <= t; ++kt) {
        const ushort_t* kp = kbase + (size_t)kt * 4096;
        const ushort_t* vp = vbase + (size_t)kt * 4096;
        s8v kf[4][2], vf[4][2];
#pragma unroll
        for (int kc = 0; kc < 2; ++kc)
#pragma unroll
            for (int nt = 0; nt < 4; ++nt) {
                kf[nt][kc] = *(const s8v*)(kp + ((kc * 4 + nt) * 64 + lane) * 8);
                vf[nt][kc] = *(const s8v*)(vp + ((kc * 4 + nt) * 64 + lane) * 8);
            }

        f4v S[2][4];
#pragma unroll
        for (int mi = 0; mi < 2; ++mi)
#pragma unroll
            for (int nt = 0; nt < 4; ++nt) S[mi][nt] = fz;
#pragma unroll
        for (int kc = 0; kc < 2; ++kc)
#pragma unroll
            for (int nt = 0; nt < 4; ++nt)
#pragma unroll
                for (int mi = 0; mi < 2; ++mi)
                    S[mi][nt] = mfma16(qf[mi][kc], kf[nt][kc], S[mi][nt]);

        if (kt == t) {                                   // diagonal tile: causal mask
#pragma unroll
            for (int mi = 0; mi < 2; ++mi)
#pragma unroll
                for (int nt = 0; nt < 4; ++nt) {
                    int key = t * 64 + nt * 16 + c;
#pragma unroll
                    for (int r = 0; r < 4; ++r) {
                        int qrow = q0 + mi * 16 + q4 * 4 + r;
                        if (key > qrow) S[mi][nt][r] = -1.0e30f;
                    }
                }
        }

        // exp2 (log2 domain), accumulate L, pack 4 bf16 -> one b64 LDS write per (mi,r)
#pragma unroll
        for (int mi = 0; mi < 2; ++mi)
#pragma unroll
            for (int r = 0; r < 4; ++r) {
                float p0 = fexp2(S[mi][0][r]), p1 = fexp2(S[mi][1][r]);
                float p2 = fexp2(S[mi][2][r]), p3 = fexp2(S[mi][3][r]);
                Lp[mi][r] += (p0 + p1) + (p2 + p3);
                int2 w_; w_.x = (int)pack_bf2(p0, p1); w_.y = (int)pack_bf2(p2, p3);
                *(int2*)(Pw + (mi * 16 + q4 * 4 + r) * 72 + c * 4) = w_;   // sigma: k' = c*4+nt
            }
        s8v pa[2][2];
#pragma unroll
        for (int mi = 0; mi < 2; ++mi)
#pragma unroll
            for (int kc = 0; kc < 2; ++kc)
                pa[mi][kc] = *(const s8v*)(Pw + (mi * 16 + c) * 72 + kc * 32 + q4 * 8);
#pragma unroll
        for (int kc = 0; kc < 2; ++kc)
#pragma unroll
            for (int dt = 0; dt < 4; ++dt)
#pragma unroll
                for (int mi = 0; mi < 2; ++mi)
                    Oacc[mi][dt] = mfma16(pa[mi][kc], vf[dt][kc], Oacc[mi][dt]);
    }

    // end-of-wave L reduction across the 16 key-col lanes
#pragma unroll
    for (int mi = 0; mi < 2; ++mi)
#pragma unroll
        for (int r = 0; r < 4; ++r)
#pragma unroll
            for (int off = 1; off < 16; off <<= 1)
                Lp[mi][r] += __shfl_xor(Lp[mi][r], off);

    const float sk = sinks[h];
#pragma unroll
    for (int mi = 0; mi < 2; ++mi)
#pragma unroll
        for (int r = 0; r < 4; ++r) {
            float L = Lp[mi][r];
            float lse = __logf(L);
            float sig = 1.f / (1.f + __expf(sk - lse));
            float sc  = sig / L;
            int row = q0 + mi * 16 + q4 * 4 + r;
#pragma unroll
            for (int dt = 0; dt < 4; ++dt)
                Ob[(size_t)row * 2048 + h * 64 + dt * 16 + c] = f2bf(Oacc[mi][dt][r] * sc);
        }
}

// ---------------- launch ----------------
extern "C" void kernel_launch(void* const* d_in, const int* in_sizes, int n_in,
                              void* d_out, int out_size, void* d_ws, size_t ws_size,
                              hipStream_t stream)
{
    (void)in_sizes; (void)n_in; (void)out_size; (void)ws_size;
    const float* x     = (const float*)d_in[0];
    const float* rope  = (const float*)d_in[1];
    const float* wq    = (const float*)d_in[2];
    const float* qb    = (const float*)d_in[3];
    const float* wk    = (const float*)d_in[4];
    const float* kb    = (const float*)d_in[5];
    const float* wv    = (const float*)d_in[6];
    const float* vb    = (const float*)d_in[7];
    const float* wo    = (const float*)d_in[8];
    const float* wob_f = (const float*)d_in[9];
    const float* sinks = (const float*)d_in[10];
    float* out = (float*)d_out;

    char* ws = (char*)d_ws;
    ushort_t* xb   = (ushort_t*)(ws);                       //  0 .. 8 MB   x bf16
    ushort_t* wqb  = (ushort_t*)(ws + (8ull  << 20));       //  8 .. 16     wq bf16
    ushort_t* wkb  = (ushort_t*)(ws + (16ull << 20));       // 16 .. 18     wk bf16
    ushort_t* wvb  = (ushort_t*)(ws + (18ull << 20));       // 18 .. 20     wv bf16
    ushort_t* wob  = (ushort_t*)(ws + (20ull << 20));       // 20 .. 28     wo bf16
    ushort_t* qo   = (ushort_t*)(ws + (28ull << 20));       // 28 .. 36     Q roped*scale*log2e
    ushort_t* kblk = (ushort_t*)(ws + (36ull << 20));       // 36 .. 38     K blocked
    ushort_t* vblk = (ushort_t*)(ws + (38ull << 20));       // 38 .. 40     V blocked
    ushort_t* ao   = (ushort_t*)(ws + (40ull << 20));       // 40 .. 48     attn out

    cast_all<<<14336, 256, 0, stream>>>(x, wq, wk, wv, wo, xb, wqb, wkb, wvb, wob);
    qkv_gemm<<<dim3(48, 16), 256, 0, stream>>>(xb, wqb, wkb, wvb, qb, kb, vb, rope, qo, kblk, vblk);
    attn_kernel<<<dim3(32, 32), 128, 0, stream>>>(qo, kblk, vblk, sinks, ao);
    proj_gemm<<<dim3(32, 16), 256, 0, stream>>>(ao, wob, wob_f, out);
}